// Round 7
// baseline (548.745 us; speedup 1.0000x reference)
//
#include <hip/hip_runtime.h>
#include <hip/hip_cooperative_groups.h>

namespace cg = cooperative_groups;

// GCN 2-layer, N=100k, E=3.2M, IN=2, HID=64, OUT=1 (all float32).
// R7: single cooperative kernel, 7 phases with grid.sync:
//   sort (staged counting sort by dest bucket, 49 buckets x 2048 nodes)
//   -> hist -> post1(dinv,y) -> s1 -> post2(MLP->t) -> s2 -> post3(out).
// LDS capped at ~31KB so 2 blocks/CU co-reside (512 blocks x 512 thr).
// C=10 chunks/bucket cuts partial traffic 136MB->32MB vs R6.
// Fallback: same phases as 7 normal launches if coop launch fails.

#define NBUCK 49
#define LBITS 11
#define BSH   2048
#define RBITS 17
#define RMASK ((1 << RBITS) - 1)
#define CAP   70000      // packed region per bucket (mean 65.3k, +18 sigma)
#define SCAP  160        // per-block per-bucket staging (mean 128, +2.9 sigma; fallback path for overflow)
#define GRID  512
#define TPB   512
#define CCH   10         // chunks per bucket in scan phases (490 active blocks)

struct SortS { int fill[NBUCK]; int gb[NBUCK]; int stage[NBUCK * SCAP]; };
struct WS    { float w1a[64], w1b[64], bb1[64], w2[64]; };
union Smem {
    SortS  sort;     // 31,752 B
    int    hist[BSH];
    float2 acc2[BSH];
    float  acc1[BSH];
    WS     w;
};

__global__ void k_init0(int* __restrict__ gcur) {
    if (threadIdx.x < NBUCK) gcur[threadIdx.x] = threadIdx.x * CAP;
}

// ---- phase bodies (shared between fused cooperative kernel and fallback) ----

__device__ void ph_sort(Smem& sm, int bid, int tid,
                        const int* __restrict__ row, const int* __restrict__ col,
                        int* __restrict__ gcur, int* __restrict__ packed, int E) {
    for (int i = tid; i < NBUCK; i += TPB) sm.sort.fill[i] = 0;
    __syncthreads();
    const int e0 = (int)((long long)bid * E / GRID);
    const int e1 = (int)((long long)(bid + 1) * E / GRID);
    for (int e = e0 + tid; e < e1; e += TPB) {
        int c = col[e];
        int b = c >> LBITS;
        int w = ((c & (BSH - 1)) << RBITS) | row[e];
        int p = atomicAdd(&sm.sort.fill[b], 1);
        if (p < SCAP) sm.sort.stage[b * SCAP + p] = w;
        else packed[atomicAdd(&gcur[b], 1)] = w;   // rare overflow, still correct
    }
    __syncthreads();
    if (tid < NBUCK) {
        int cnt = min(sm.sort.fill[tid], SCAP);
        sm.sort.gb[tid] = atomicAdd(&gcur[tid], cnt);
    }
    __syncthreads();
    const int wid = tid >> 6, lane = tid & 63;
    for (int b = wid; b < NBUCK; b += (TPB / 64)) {   // per-wave coalesced copy-out
        int cnt = min(sm.sort.fill[b], SCAP);
        int gp = sm.sort.gb[b];
        for (int i = lane; i < cnt; i += 64)
            packed[gp + i] = sm.sort.stage[b * SCAP + i];
    }
}

__device__ void ph_hist(Smem& sm, int bid, int tid,
                        const int* __restrict__ gcur, const int* __restrict__ packed,
                        int* __restrict__ pbi) {
    if (bid >= NBUCK * CCH) return;
    const int b = bid / CCH, j = bid - b * CCH;
    for (int i = tid; i < BSH; i += TPB) sm.hist[i] = 0;
    __syncthreads();
    const int base = b * CAP;
    const int len = gcur[b] - base;
    const int a0 = base + (int)((long long)len * j / CCH);
    const int a1 = base + (int)((long long)len * (j + 1) / CCH);
    for (int e = a0 + tid; e < a1; e += TPB)
        atomicAdd(&sm.hist[packed[e] >> RBITS], 1);
    __syncthreads();
    int4* dst = (int4*)(pbi + (bid << LBITS));
    const int4* src = (const int4*)sm.hist;
    for (int i = tid; i < (BSH >> 2); i += TPB) dst[i] = src[i];
}

__device__ void ph_post1(int i1, const int* __restrict__ pbi,
                         const float2* __restrict__ x,
                         float* __restrict__ dinv, float2* __restrict__ y, int n) {
    if (i1 >= n) return;
    const int b = i1 >> LBITS, l = i1 & (BSH - 1);
    int deg = 1;  // self-loop
    const int* p = pbi + ((b * CCH) << LBITS) + l;
#pragma unroll
    for (int j = 0; j < CCH; ++j) deg += p[j << LBITS];
    float d = rsqrtf((float)deg);
    dinv[i1] = d;
    float2 xv = x[i1];
    y[i1] = make_float2(d * xv.x, d * xv.y);
}

__device__ void ph_s1(Smem& sm, int bid, int tid,
                      const int* __restrict__ gcur, const int* __restrict__ packed,
                      const float2* __restrict__ y, float2* __restrict__ pbf2) {
    if (bid >= NBUCK * CCH) return;
    const int b = bid / CCH, j = bid - b * CCH;
    for (int i = tid; i < BSH; i += TPB) sm.acc2[i] = make_float2(0.f, 0.f);
    __syncthreads();
    const int base = b * CAP;
    const int len = gcur[b] - base;
    const int a0 = base + (int)((long long)len * j / CCH);
    const int a1 = base + (int)((long long)len * (j + 1) / CCH);
    for (int e = a0 + tid; e < a1; e += TPB) {
        int w = packed[e];
        float2 v = y[w & RMASK];
        float* sp = (float*)&sm.acc2[w >> RBITS];
        atomicAdd(sp, v.x);
        atomicAdd(sp + 1, v.y);
    }
    __syncthreads();
    float4* dst = (float4*)(pbf2 + (bid << LBITS));
    const float4* src = (const float4*)sm.acc2;
    for (int i = tid; i < (BSH >> 1); i += TPB) dst[i] = src[i];
}

__device__ void ph_post2(Smem& sm, int i1, int tid,
                         const float2* __restrict__ pbf2,
                         const float* __restrict__ dinv, const float2* __restrict__ y,
                         const float* __restrict__ W1, const float* __restrict__ B1,
                         const float* __restrict__ W2,
                         float* __restrict__ t, int n) {
    if (tid < 64) {
        sm.w.w1a[tid] = W1[tid];
        sm.w.w1b[tid] = W1[64 + tid];
        sm.w.bb1[tid] = B1[tid];
        sm.w.w2[tid]  = W2[tid];
    }
    __syncthreads();
    if (i1 >= n) return;
    const int b = i1 >> LBITS, l = i1 & (BSH - 1);
    float gx = 0.f, gy = 0.f;
    const float2* p = pbf2 + ((b * CCH) << LBITS) + l;
#pragma unroll
    for (int j = 0; j < CCH; ++j) { float2 v = p[j << LBITS]; gx += v.x; gy += v.y; }
    float d = dinv[i1];
    float2 yv = y[i1];
    float a0 = d * (gx + yv.x);
    float a1 = d * (gy + yv.y);
    float acc = 0.f;
#pragma unroll
    for (int h = 0; h < 64; ++h) {
        float v = fmaf(a0, sm.w.w1a[h], fmaf(a1, sm.w.w1b[h], sm.w.bb1[h]));
        acc = fmaf(fmaxf(v, 0.f), sm.w.w2[h], acc);
    }
    t[i1] = d * acc;
}

__device__ void ph_s2(Smem& sm, int bid, int tid,
                      const int* __restrict__ gcur, const int* __restrict__ packed,
                      const float* __restrict__ t, float* __restrict__ pbf) {
    if (bid >= NBUCK * CCH) return;
    const int b = bid / CCH, j = bid - b * CCH;
    for (int i = tid; i < BSH; i += TPB) sm.acc1[i] = 0.f;
    __syncthreads();
    const int base = b * CAP;
    const int len = gcur[b] - base;
    const int a0 = base + (int)((long long)len * j / CCH);
    const int a1 = base + (int)((long long)len * (j + 1) / CCH);
    for (int e = a0 + tid; e < a1; e += TPB) {
        int w = packed[e];
        atomicAdd(&sm.acc1[w >> RBITS], t[w & RMASK]);
    }
    __syncthreads();
    float4* dst = (float4*)(pbf + (bid << LBITS));
    const float4* src = (const float4*)sm.acc1;
    for (int i = tid; i < (BSH >> 2); i += TPB) dst[i] = src[i];
}

__device__ void ph_post3(int i1, const float* __restrict__ pbf,
                         const float* __restrict__ t, const float* __restrict__ dinv,
                         const float* __restrict__ B2, float* __restrict__ out, int n) {
    if (i1 >= n) return;
    const int b = i1 >> LBITS, l = i1 & (BSH - 1);
    float o = 0.f;
    const float* p = pbf + ((b * CCH) << LBITS) + l;
#pragma unroll
    for (int j = 0; j < CCH; ++j) o += p[j << LBITS];
    out[i1] = fmaf(dinv[i1], o + t[i1], B2[0]);
}

// ---- fused cooperative kernel ----
__global__ void __launch_bounds__(TPB, 4)
k_fused(const float2* __restrict__ x, const int* __restrict__ row,
        const int* __restrict__ col,
        const float* __restrict__ W1, const float* __restrict__ B1,
        const float* __restrict__ W2, const float* __restrict__ B2,
        int* __restrict__ gcur, int* __restrict__ packed, float* __restrict__ pb,
        float* __restrict__ dinv, float2* __restrict__ y, float* __restrict__ t,
        float* __restrict__ out, int n, int E) {
    __shared__ Smem sm;
    cg::grid_group g = cg::this_grid();
    const int tid = threadIdx.x, bid = blockIdx.x;
    const int i1 = bid * TPB + tid;

    ph_sort(sm, bid, tid, row, col, gcur, packed, E);
    g.sync();
    ph_hist(sm, bid, tid, gcur, packed, (int*)pb);
    g.sync();
    ph_post1(i1, (const int*)pb, x, dinv, y, n);
    g.sync();
    ph_s1(sm, bid, tid, gcur, packed, y, (float2*)pb);
    g.sync();
    ph_post2(sm, i1, tid, (const float2*)pb, dinv, y, W1, B1, W2, t, n);
    g.sync();
    ph_s2(sm, bid, tid, gcur, packed, t, pb);
    g.sync();
    ph_post3(i1, pb, t, dinv, B2, out, n);
}

// ---- fallback wrappers (normal launches) ----
__global__ void kw_sort(const int* row, const int* col, int* gcur, int* packed, int E) {
    __shared__ Smem sm; ph_sort(sm, blockIdx.x, threadIdx.x, row, col, gcur, packed, E);
}
__global__ void kw_hist(const int* gcur, const int* packed, int* pbi) {
    __shared__ Smem sm; ph_hist(sm, blockIdx.x, threadIdx.x, gcur, packed, pbi);
}
__global__ void kw_post1(const int* pbi, const float2* x, float* dinv, float2* y, int n) {
    ph_post1(blockIdx.x * TPB + threadIdx.x, pbi, x, dinv, y, n);
}
__global__ void kw_s1(const int* gcur, const int* packed, const float2* y, float2* pbf2) {
    __shared__ Smem sm; ph_s1(sm, blockIdx.x, threadIdx.x, gcur, packed, y, pbf2);
}
__global__ void kw_post2(const float2* pbf2, const float* dinv, const float2* y,
                         const float* W1, const float* B1, const float* W2,
                         float* t, int n) {
    __shared__ Smem sm;
    ph_post2(sm, blockIdx.x * TPB + threadIdx.x, threadIdx.x, pbf2, dinv, y, W1, B1, W2, t, n);
}
__global__ void kw_s2(const int* gcur, const int* packed, const float* t, float* pbf) {
    __shared__ Smem sm; ph_s2(sm, blockIdx.x, threadIdx.x, gcur, packed, t, pbf);
}
__global__ void kw_post3(const float* pbf, const float* t, const float* dinv,
                         const float* B2, float* out, int n) {
    ph_post3(blockIdx.x * TPB + threadIdx.x, pbf, t, dinv, B2, out, n);
}

extern "C" void kernel_launch(void* const* d_in, const int* in_sizes, int n_in,
                              void* d_out, int out_size, void* d_ws, size_t ws_size,
                              hipStream_t stream) {
    const float* x  = (const float*)d_in[0];
    const int*   ei = (const int*)d_in[1];
    const float* W1 = (const float*)d_in[2];
    const float* B1 = (const float*)d_in[3];
    const float* W2 = (const float*)d_in[4];
    const float* B2 = (const float*)d_in[5];
    float* out = (float*)d_out;

    int n = in_sizes[0] / 2;      // 100,000
    int E = in_sizes[1] / 2;      // 3,200,000
    const int* row = ei;
    const int* col = ei + E;

    // ws: dinv[n] | y[n](f2) | t[n] | gcur | packed[49*CAP] | pb (<=8.1MB)
    char* ws = (char*)d_ws;
    size_t off = 0;
    float*  dinv = (float*)(ws + off);  off += (size_t)n * 4;
    float2* y    = (float2*)(ws + off); off += (size_t)n * 8;
    float*  t    = (float*)(ws + off);  off += (size_t)n * 4;
    off = (off + 255) & ~(size_t)255;
    int* gcur    = (int*)(ws + off);    off += 256;
    int* packed  = (int*)(ws + off);    off += (size_t)NBUCK * CAP * 4;
    off = (off + 255) & ~(size_t)255;
    float* pb    = (float*)(ws + off);

    k_init0<<<1, 64, 0, stream>>>(gcur);

    const float2* x2 = (const float2*)x;
    void* args[] = { (void*)&x2, (void*)&row, (void*)&col, (void*)&W1, (void*)&B1,
                     (void*)&W2, (void*)&B2, (void*)&gcur, (void*)&packed, (void*)&pb,
                     (void*)&dinv, (void*)&y, (void*)&t, (void*)&out,
                     (void*)&n, (void*)&E };
    hipError_t err = hipLaunchCooperativeKernel((const void*)k_fused, dim3(GRID),
                                                dim3(TPB), args, 0, stream);
    if (err != hipSuccess) {
        (void)hipGetLastError();   // clear, take the multi-launch path
        const int gnode = (n + TPB - 1) / TPB;
        kw_sort <<<GRID, TPB, 0, stream>>>(row, col, gcur, packed, E);
        kw_hist <<<NBUCK * CCH, TPB, 0, stream>>>(gcur, packed, (int*)pb);
        kw_post1<<<gnode, TPB, 0, stream>>>((const int*)pb, x2, dinv, y, n);
        kw_s1   <<<NBUCK * CCH, TPB, 0, stream>>>(gcur, packed, y, (float2*)pb);
        kw_post2<<<gnode, TPB, 0, stream>>>((const float2*)pb, dinv, y, W1, B1, W2, t, n);
        kw_s2   <<<NBUCK * CCH, TPB, 0, stream>>>(gcur, packed, t, pb);
        kw_post3<<<gnode, TPB, 0, stream>>>(pb, t, dinv, B2, out, n);
    }
}

// Round 8
// 170.434 us; speedup vs baseline: 3.2197x; 3.2197x over previous
//
#include <hip/hip_runtime.h>

// GCN 2-layer, N=100k, E=3.2M, IN=2, HID=64, OUT=1 (all float32).
// R8: R7's phase pipeline as 8 plain launches (coop grid.sync cost ~70us/sync
// -> 460us kernel; reverted). 49 buckets x 2048 nodes, staged counting sort
// (int4 edge loads), then hist/s1/s2 scans read each edge once and accumulate
// in right-sized LDS (8/16/8 KB -> 4 blocks/CU), C=10 partials/bucket
// (32MB partial traffic vs R6's 136MB). Zero global atomics on hot paths.

#define NBUCK 49
#define LBITS 11
#define BSH   2048
#define RBITS 17
#define RMASK ((1 << RBITS) - 1)
#define CAP   70000      // packed region per bucket (mean 65.5k, ~18 sigma)
#define SCAP  160        // per-block per-bucket staging (mean 128, ~2.9 sigma)
#define SORTB 512
#define TPB   512
#define TPN   256
#define CCH   10         // chunks per bucket in scans (490 blocks)

__global__ void k_init0(int* __restrict__ gcur) {
    if (threadIdx.x < NBUCK) gcur[threadIdx.x] = threadIdx.x * CAP;
}

// staged counting sort by dest bucket: packed[b] gets ((lcol<<RBITS)|row)
__global__ void __launch_bounds__(TPB)
k_sort(const int* __restrict__ row, const int* __restrict__ col,
       int* __restrict__ gcur, int* __restrict__ packed, int E) {
    __shared__ int fill[NBUCK];
    __shared__ int gb[NBUCK];
    __shared__ int stage[NBUCK * SCAP];   // 31,360 B -> 2 blocks/CU
    const int tid = threadIdx.x, bid = blockIdx.x;
    if (tid < NBUCK) fill[tid] = 0;
    __syncthreads();
    const int q = E >> 2;
    const int q0 = (int)((long long)bid * q / SORTB);
    const int q1 = (int)((long long)(bid + 1) * q / SORTB);
    const int4* col4 = (const int4*)col;
    const int4* row4 = (const int4*)row;
    for (int i = q0 + tid; i < q1; i += TPB) {
        int4 c = col4[i], r = row4[i];
        int b, w, p;
        b = c.x >> LBITS; w = ((c.x & (BSH - 1)) << RBITS) | r.x;
        p = atomicAdd(&fill[b], 1);
        if (p < SCAP) stage[b * SCAP + p] = w; else packed[atomicAdd(&gcur[b], 1)] = w;
        b = c.y >> LBITS; w = ((c.y & (BSH - 1)) << RBITS) | r.y;
        p = atomicAdd(&fill[b], 1);
        if (p < SCAP) stage[b * SCAP + p] = w; else packed[atomicAdd(&gcur[b], 1)] = w;
        b = c.z >> LBITS; w = ((c.z & (BSH - 1)) << RBITS) | r.z;
        p = atomicAdd(&fill[b], 1);
        if (p < SCAP) stage[b * SCAP + p] = w; else packed[atomicAdd(&gcur[b], 1)] = w;
        b = c.w >> LBITS; w = ((c.w & (BSH - 1)) << RBITS) | r.w;
        p = atomicAdd(&fill[b], 1);
        if (p < SCAP) stage[b * SCAP + p] = w; else packed[atomicAdd(&gcur[b], 1)] = w;
    }
    if (bid == SORTB - 1) {   // scalar tail if E%4 != 0
        for (int e = (q << 2) + tid; e < E; e += TPB) {
            int c = col[e];
            int b = c >> LBITS, w = ((c & (BSH - 1)) << RBITS) | row[e];
            int p = atomicAdd(&fill[b], 1);
            if (p < SCAP) stage[b * SCAP + p] = w; else packed[atomicAdd(&gcur[b], 1)] = w;
        }
    }
    __syncthreads();
    if (tid < NBUCK) {
        int cnt = min(fill[tid], SCAP);
        gb[tid] = atomicAdd(&gcur[tid], cnt);
    }
    __syncthreads();
    const int wid = tid >> 6, lane = tid & 63;
    for (int b = wid; b < NBUCK; b += (TPB >> 6)) {   // per-wave coalesced copy-out
        int cnt = min(fill[b], SCAP);
        int gp = gb[b];
        for (int i = lane; i < cnt; i += 64)
            packed[gp + i] = stage[b * SCAP + i];
    }
}

// in-degree histogram from bucket-sorted packed edges (8KB LDS)
__global__ void __launch_bounds__(TPB)
k_hist(const int* __restrict__ gcur, const int* __restrict__ packed,
       int* __restrict__ pbi) {
    __shared__ int s[BSH];
    const int b = blockIdx.x / CCH, j = blockIdx.x - b * CCH;
    for (int i = threadIdx.x; i < BSH; i += TPB) s[i] = 0;
    __syncthreads();
    const int base = b * CAP;
    const int len = gcur[b] - base;
    const int a0 = base + (int)((long long)len * j / CCH);
    const int a1 = base + (int)((long long)len * (j + 1) / CCH);
    for (int e = a0 + threadIdx.x; e < a1; e += TPB)
        atomicAdd(&s[packed[e] >> RBITS], 1);
    __syncthreads();
    int4* dst = (int4*)(pbi + ((size_t)blockIdx.x << LBITS));
    const int4* src = (const int4*)s;
    for (int i = threadIdx.x; i < (BSH >> 2); i += TPB) dst[i] = src[i];
}

// merge hist partials -> dinv; y = dinv*x
__global__ void __launch_bounds__(TPN)
k_post1(const int* __restrict__ pbi, const float2* __restrict__ x,
        float* __restrict__ dinv, float2* __restrict__ y, int n) {
    int i = blockIdx.x * TPN + threadIdx.x;
    if (i >= n) return;
    const int b = i >> LBITS, l = i & (BSH - 1);
    int deg = 1;  // self-loop
    const int* p = pbi + ((size_t)(b * CCH) << LBITS) + l;
#pragma unroll
    for (int j = 0; j < CCH; ++j) deg += p[j << LBITS];
    float d = rsqrtf((float)deg);
    dinv[i] = d;
    float2 xv = x[i];
    y[i] = make_float2(d * xv.x, d * xv.y);
}

// layer-1 scatter: s[lcol] += y[row] (16KB LDS)
__global__ void __launch_bounds__(TPB)
k_s1(const int* __restrict__ gcur, const int* __restrict__ packed,
     const float2* __restrict__ y, float2* __restrict__ pbf2) {
    __shared__ float2 s[BSH];
    const int b = blockIdx.x / CCH, j = blockIdx.x - b * CCH;
    for (int i = threadIdx.x; i < BSH; i += TPB) s[i] = make_float2(0.f, 0.f);
    __syncthreads();
    const int base = b * CAP;
    const int len = gcur[b] - base;
    const int a0 = base + (int)((long long)len * j / CCH);
    const int a1 = base + (int)((long long)len * (j + 1) / CCH);
    for (int e = a0 + threadIdx.x; e < a1; e += TPB) {
        int w = packed[e];
        float2 v = y[w & RMASK];
        float* sp = (float*)&s[w >> RBITS];
        atomicAdd(sp, v.x);
        atomicAdd(sp + 1, v.y);
    }
    __syncthreads();
    float4* dst = (float4*)(pbf2 + ((size_t)blockIdx.x << LBITS));
    const float4* src = (const float4*)s;
    for (int i = threadIdx.x; i < (BSH >> 1); i += TPB) dst[i] = src[i];
}

// merge layer-1 partials + per-node MLP: t = dinv*(relu(a@W1+b1)@W2)
__global__ void __launch_bounds__(TPN)
k_post2(const float2* __restrict__ pbf2, const float* __restrict__ dinv,
        const float2* __restrict__ y,
        const float* __restrict__ W1, const float* __restrict__ B1,
        const float* __restrict__ W2, float* __restrict__ t, int n) {
    __shared__ float w1a[64], w1b[64], bb1[64], w2[64];
    if (threadIdx.x < 64) {
        w1a[threadIdx.x] = W1[threadIdx.x];
        w1b[threadIdx.x] = W1[64 + threadIdx.x];
        bb1[threadIdx.x] = B1[threadIdx.x];
        w2[threadIdx.x]  = W2[threadIdx.x];
    }
    __syncthreads();
    int i = blockIdx.x * TPN + threadIdx.x;
    if (i >= n) return;
    const int b = i >> LBITS, l = i & (BSH - 1);
    float gx = 0.f, gy = 0.f;
    const float2* p = pbf2 + ((size_t)(b * CCH) << LBITS) + l;
#pragma unroll
    for (int j = 0; j < CCH; ++j) { float2 v = p[j << LBITS]; gx += v.x; gy += v.y; }
    float d = dinv[i];
    float2 yv = y[i];
    float a0 = d * (gx + yv.x);
    float a1 = d * (gy + yv.y);
    float acc = 0.f;
#pragma unroll
    for (int h = 0; h < 64; ++h) {
        float v = fmaf(a0, w1a[h], fmaf(a1, w1b[h], bb1[h]));
        acc = fmaf(fmaxf(v, 0.f), w2[h], acc);
    }
    t[i] = d * acc;
}

// layer-2 scatter: s[lcol] += t[row] (8KB LDS)
__global__ void __launch_bounds__(TPB)
k_s2(const int* __restrict__ gcur, const int* __restrict__ packed,
     const float* __restrict__ t, float* __restrict__ pbf) {
    __shared__ float s[BSH];
    const int b = blockIdx.x / CCH, j = blockIdx.x - b * CCH;
    for (int i = threadIdx.x; i < BSH; i += TPB) s[i] = 0.f;
    __syncthreads();
    const int base = b * CAP;
    const int len = gcur[b] - base;
    const int a0 = base + (int)((long long)len * j / CCH);
    const int a1 = base + (int)((long long)len * (j + 1) / CCH);
    for (int e = a0 + threadIdx.x; e < a1; e += TPB) {
        int w = packed[e];
        atomicAdd(&s[w >> RBITS], t[w & RMASK]);
    }
    __syncthreads();
    float4* dst = (float4*)(pbf + ((size_t)blockIdx.x << LBITS));
    const float4* src = (const float4*)s;
    for (int i = threadIdx.x; i < (BSH >> 2); i += TPB) dst[i] = src[i];
}

// merge layer-2 partials + epilogue
__global__ void __launch_bounds__(TPN)
k_post3(const float* __restrict__ pbf, const float* __restrict__ t,
        const float* __restrict__ dinv, const float* __restrict__ B2,
        float* __restrict__ out, int n) {
    int i = blockIdx.x * TPN + threadIdx.x;
    if (i >= n) return;
    const int b = i >> LBITS, l = i & (BSH - 1);
    float o = 0.f;
    const float* p = pbf + ((size_t)(b * CCH) << LBITS) + l;
#pragma unroll
    for (int j = 0; j < CCH; ++j) o += p[j << LBITS];
    out[i] = fmaf(dinv[i], o + t[i], B2[0]);
}

extern "C" void kernel_launch(void* const* d_in, const int* in_sizes, int n_in,
                              void* d_out, int out_size, void* d_ws, size_t ws_size,
                              hipStream_t stream) {
    const float* x  = (const float*)d_in[0];
    const int*   ei = (const int*)d_in[1];
    const float* W1 = (const float*)d_in[2];
    const float* B1 = (const float*)d_in[3];
    const float* W2 = (const float*)d_in[4];
    const float* B2 = (const float*)d_in[5];
    float* out = (float*)d_out;

    const int n = in_sizes[0] / 2;      // 100,000
    const int E = in_sizes[1] / 2;      // 3,200,000
    const int* row = ei;
    const int* col = ei + E;

    // ws: dinv[n] | y[n](f2) | t[n] | gcur | packed[49*CAP] | pb (8MB)
    char* ws = (char*)d_ws;
    size_t off = 0;
    float*  dinv = (float*)(ws + off);  off += (size_t)n * 4;
    float2* y    = (float2*)(ws + off); off += (size_t)n * 8;
    float*  t    = (float*)(ws + off);  off += (size_t)n * 4;
    off = (off + 255) & ~(size_t)255;
    int* gcur    = (int*)(ws + off);    off += 256;
    int* packed  = (int*)(ws + off);    off += (size_t)NBUCK * CAP * 4;
    off = (off + 255) & ~(size_t)255;
    float* pb    = (float*)(ws + off);

    const int gnode = (n + TPN - 1) / TPN;
    const int gscan = NBUCK * CCH;

    k_init0<<<1, 64, 0, stream>>>(gcur);
    k_sort <<<SORTB, TPB, 0, stream>>>(row, col, gcur, packed, E);
    k_hist <<<gscan, TPB, 0, stream>>>(gcur, packed, (int*)pb);
    k_post1<<<gnode, TPN, 0, stream>>>((const int*)pb, (const float2*)x, dinv, y, n);
    k_s1   <<<gscan, TPB, 0, stream>>>(gcur, packed, y, (float2*)pb);
    k_post2<<<gnode, TPN, 0, stream>>>((const float2*)pb, dinv, y, W1, B1, W2, t, n);
    k_s2   <<<gscan, TPB, 0, stream>>>(gcur, packed, t, pb);
    k_post3<<<gnode, TPN, 0, stream>>>(pb, t, dinv, B2, out, n);
}